// Round 28
// baseline (147.024 us; speedup 1.0000x reference)
//
#include <hip/hip_runtime.h>
#include <stdint.h>

typedef __bf16 bf16x8 __attribute__((ext_vector_type(8)));
typedef float f32x4 __attribute__((ext_vector_type(4)));

#define NSAMPLE 64
static constexpr int Bb = 4, Nn = 16384, Mm = 1024, Cc = 256;

__device__ __forceinline__ unsigned short f2bf(float f) {   // exact RTNE via bit ops (cold paths)
  unsigned int u = __builtin_bit_cast(unsigned int, f);
  u = u + 0x7fffu + ((u >> 16) & 1u);
  return (unsigned short)(u >> 16);
}
__device__ __forceinline__ unsigned short f2bf_cvt(float f) {  // hardware cvt (hot paths)
  return __builtin_bit_cast(unsigned short, (__bf16)f);
}
__device__ __forceinline__ float bf2f(unsigned short u) {
  return __builtin_bit_cast(float, (unsigned int)u << 16);
}

// async global->LDS, 16B per lane; LDS dest = wave-uniform base + lane*16
__device__ __forceinline__ void gload_lds16(const void* g, void* lds) {
  __builtin_amdgcn_global_load_lds(
      (const __attribute__((address_space(1))) uint32_t*)g,
      (__attribute__((address_space(3))) uint32_t*)lds, 16, 0, 0);
}

// ---- prep: SEPARATE LAUNCH (k2's X1all consumes W1b; launch boundary = the only ordering) ----
__global__ void prep_kernel(const float* __restrict__ W1, const float* __restrict__ b1,
                            const float* __restrict__ g1, const float* __restrict__ be1,
                            const float* __restrict__ m1, const float* __restrict__ v1,
                            const float* __restrict__ W2, const float* __restrict__ b2,
                            const float* __restrict__ g2, const float* __restrict__ be2,
                            const float* __restrict__ m2, const float* __restrict__ v2,
                            unsigned short* __restrict__ W1b, float* __restrict__ w1c,
                            float* __restrict__ b1e,
                            unsigned short* __restrict__ W2b, float* __restrict__ b2e) {
  int t = blockIdx.x * 256 + threadIdx.x;   // 65536 threads
  {
    int o = t >> 8, k = t & 255;
    float s1 = g1[o] / sqrtf(v1[o] + 1e-5f);
    W1b[t] = f2bf(W1[o * 259 + 3 + k] * s1);
    float s2 = g2[o] / sqrtf(v2[o] + 1e-5f);
    W2b[t] = f2bf(W2[t] * s2);
  }
  if (t < 256 * 3) {
    int o = t / 3, c = t - o * 3;
    float s = g1[o] / sqrtf(v1[o] + 1e-5f);
    w1c[t] = W1[o * 259 + c] * s;
  }
  if (t < 256) {
    float s1 = g1[t] / sqrtf(v1[t] + 1e-5f);
    b1e[t] = s1 * (b1[t] - m1[t]) + be1[t];
    float s2 = g2[t] / sqrtf(v2[t] + 1e-5f);
    b2e[t] = s2 * (b2[t] - m2[t]) + be2[t];
  }
}

// ---- K2: blocks 0..1023 ballq (latency pole, dispatched first); 1024..2047 X1all GEMM -------
// Overlapping latency-bound scan with memory-bound GEMM (R25-proven arrangement).
__global__ __launch_bounds__(256, 4) void k2_kernel(
    const float* __restrict__ xyz, const float* __restrict__ new_xyz,
    const float* __restrict__ feats, const unsigned short* __restrict__ W1b,
    unsigned short* __restrict__ X1all, int* __restrict__ idx) {
  __shared__ __align__(16) char smem[32768 + 64];
  int bx = blockIdx.x;
  int t = threadIdx.x;
  if (bx < 1024) {
    int* wl = (int*)smem;               // [(qi*4+w)*64+slot]
    int* wcnt = (int*)(smem + 32768);   // [qi*4+w]
    const float r2 = (float)(0.08 * 0.08);
    int bm0 = bx * 4;
    int lane = t & 63, w = t >> 6;
    int b = bm0 >> 10;
    float qx[4], qy[4], qz[4], qq[4];
    int cnt[4];
#pragma unroll
    for (int qi = 0; qi < 4; qi++) {
      qx[qi] = new_xyz[(bm0 + qi) * 3];
      qy[qi] = new_xyz[(bm0 + qi) * 3 + 1];
      qz[qi] = new_xyz[(bm0 + qi) * 3 + 2];
      qq[qi] = __fadd_rn(__fadd_rn(__fmul_rn(qx[qi], qx[qi]), __fmul_rn(qy[qi], qy[qi])),
                         __fmul_rn(qz[qi], qz[qi]));
      cnt[qi] = 0;
    }
    const float* P = xyz + ((size_t)b * Nn + w * 4096) * 3;
    for (int n0 = 0; n0 < 4096; n0 += 64) {
      const float* pp = P + (n0 + lane) * 3;
      float x = pp[0], y = pp[1], z = pp[2];
      float p2 = __fadd_rn(__fadd_rn(__fmul_rn(x, x), __fmul_rn(y, y)), __fmul_rn(z, z));
#pragma unroll
      for (int qi = 0; qi < 4; qi++) {
        if (cnt[qi] >= NSAMPLE) continue;   // wave-uniform
        float dt = __fadd_rn(__fadd_rn(__fmul_rn(qx[qi], x), __fmul_rn(qy[qi], y)),
                             __fmul_rn(qz[qi], z));
        float d2 = __fsub_rn(__fadd_rn(qq[qi], p2), __fmul_rn(2.f, dt));
        bool valid = d2 < r2;
        unsigned long long mask = __ballot(valid);
        if (mask) {
          if (valid) {
            int pos = cnt[qi] + __popcll(mask & ((1ull << lane) - 1ull));
            if (pos < NSAMPLE) wl[(qi * 4 + w) * 64 + pos] = w * 4096 + n0 + lane;
          }
          cnt[qi] += (int)__popcll(mask);
        }
      }
      if (cnt[0] >= NSAMPLE && cnt[1] >= NSAMPLE && cnt[2] >= NSAMPLE && cnt[3] >= NSAMPLE)
        break;
    }
    if (lane == 0) {
#pragma unroll
      for (int qi = 0; qi < 4; qi++) wcnt[qi * 4 + w] = cnt[qi];
    }
    __syncthreads();
    {
      int qi = t >> 6, s = t & 63;
      int c0 = wcnt[qi * 4], c1 = wcnt[qi * 4 + 1], c2 = wcnt[qi * 4 + 2], c3 = wcnt[qi * 4 + 3];
      int tot = c0 + c1 + c2 + c3;
      int cc = tot < NSAMPLE ? tot : NSAMPLE;
      int v;
      if (s < cc) {
        if (s < c0) v = wl[(qi * 4 + 0) * 64 + s];
        else if (s < c0 + c1) v = wl[(qi * 4 + 1) * 64 + s - c0];
        else if (s < c0 + c1 + c2) v = wl[(qi * 4 + 2) * 64 + s - c0 - c1];
        else v = wl[(qi * 4 + 3) * 64 + s - c0 - c1 - c2];
      } else {
        v = (c0 > 0) ? wl[(qi * 4 + 0) * 64] : (c1 > 0) ? wl[(qi * 4 + 1) * 64]
          : (c2 > 0) ? wl[(qi * 4 + 2) * 64] : (c3 > 0) ? wl[(qi * 4 + 3) * 64] : 0;
      }
      idx[(size_t)(bm0 + qi) * NSAMPLE + s] = v;
    }
    return;
  }
  // ---------------- X1all GEMM, 64-row tile; full-wave-coalesced, hardware cvt ----------------
  unsigned short* Xf = (unsigned short*)smem;   // [64][256] swizzled bf16 (32 KB)
  int xb = bx - 1024;                            // 0..1023
  int b = xb >> 8, nt = xb & 255, n0 = nt * 64;
  {
    int nloc = t & 63, cgrp = t >> 6;            // one channel-group per WAVE -> 256B coalesced
    const float* src = feats + ((size_t)(b * Cc + cgrp * 64)) * Nn + n0 + nloc;
#pragma unroll
    for (int q = 0; q < 8; q++) {
      unsigned short e[8];
#pragma unroll
      for (int j = 0; j < 8; j++)
        e[j] = f2bf_cvt(src[(size_t)(q * 8 + j) * Nn]);
      int cg = cgrp * 8 + q;                     // logical chunk 0..31
      int sc = cg ^ (nloc & 7);                  // physical chunk (rule #21)
      *(uint4*)&Xf[nloc * 256 + sc * 8] = *(uint4*)e;
    }
  }
  __syncthreads();
  // [64x256]x[256x256] MFMA
  int wave = t >> 6, lane = t & 63;
  int lr = lane & 15, kg = lane >> 4;
  int wcol = wave * 64;
  f32x4 acc[4][4];
#pragma unroll
  for (int mi = 0; mi < 4; mi++)
#pragma unroll
    for (int ni = 0; ni < 4; ni++) acc[mi][ni] = (f32x4){0.f, 0.f, 0.f, 0.f};
#pragma unroll
  for (int kk = 0; kk < 8; kk++) {
    bf16x8 w[4];
#pragma unroll
    for (int ni = 0; ni < 4; ni++)
      w[ni] = *(const bf16x8*)&W1b[(size_t)(wcol + ni * 16 + lr) * 256 + kk * 32 + kg * 8];
    bf16x8 a[4];
#pragma unroll
    for (int mi = 0; mi < 4; mi++) {
      int r = mi * 16 + lr;
      int cs = ((kk * 4 + kg) ^ (r & 7)) * 8;
      a[mi] = *(const bf16x8*)&Xf[r * 256 + cs];
    }
#pragma unroll
    for (int mi = 0; mi < 4; mi++)
#pragma unroll
      for (int ni = 0; ni < 4; ni++)
        acc[mi][ni] = __builtin_amdgcn_mfma_f32_16x16x32_bf16(a[mi], w[ni], acc[mi][ni], 0, 0, 0);
  }
  __syncthreads();
  // bounce acc -> Xf LINEAR
#pragma unroll
  for (int ni = 0; ni < 4; ni++) {
    int o = wcol + ni * 16 + lr;
#pragma unroll
    for (int mi = 0; mi < 4; mi++)
#pragma unroll
      for (int j = 0; j < 4; j++) {
        int r = mi * 16 + kg * 4 + j;
        Xf[r * 256 + o] = f2bf_cvt(acc[mi][ni][j]);
      }
  }
  __syncthreads();
  // coalesced store: thread t -> row t>>2, cols (t&3)*64..+63 (8 x uint4)
  {
    int row = t >> 2, off = (t & 3) * 64;
    unsigned short* dst = X1all + ((size_t)(b * Nn + n0 + row)) * 256 + off;
#pragma unroll
    for (int i = 0; i < 8; i++)
      *(uint4*)(dst + i * 8) = *(const uint4*)&Xf[row * 256 + off + i * 8];
  }
}

// ---- fused: R27 verbatim (gather X1all -> fragment-pattern H-ify w/ cvt -> L2 MFMA -> out) ---
__global__ __launch_bounds__(256, 4) void fused_kernel(
    const unsigned short* __restrict__ X1all, const float* __restrict__ xyz,
    const float* __restrict__ new_xyz, const int* __restrict__ idx,
    const float* __restrict__ w1c, const float* __restrict__ b1e,
    const unsigned short* __restrict__ W2b, const float* __restrict__ b2e,
    float* __restrict__ out) {
  __shared__ unsigned short Xf[64 * 256];  // 32768 B swizzled; X1 gathered -> H in place
  __shared__ float Xc[3][64];
  __shared__ float Cw[4][256];             // b1e, wx, wy, wz staged
  int t = threadIdx.x;
  int wave = t >> 6, lane = t & 63;
  int lr = lane & 15, kg = lane >> 4;
  int wcol = wave * 64;
  int bm = blockIdx.x;
  int b = bm >> 10;

  {
    int idxr = idx[(size_t)bm * NSAMPLE + wave * 16 + (lane & 15)];
#pragma unroll
    for (int i = 0; i < 8; i++) {
      int j = wave * 8 + i;                       // row pair 2j, 2j+1
      int iv = __shfl(idxr, 2 * i + (lane >> 5));
      int r7 = (2 * j + (lane >> 5)) & 7;
      int cg = (lane & 31) ^ r7;                  // swizzled global chunk (rule #21)
      gload_lds16(X1all + ((size_t)b * Nn + iv) * Cc + cg * 8, &Xf[j * 512]);
    }
  }
  if (t < 64) {
    int ci = idx[(size_t)bm * NSAMPLE + t];
    const float* pp = xyz + ((size_t)b * Nn + ci) * 3;
    Xc[0][t] = pp[0] - new_xyz[bm * 3];
    Xc[1][t] = pp[1] - new_xyz[bm * 3 + 1];
    Xc[2][t] = pp[2] - new_xyz[bm * 3 + 2];
  }
  {
    Cw[0][t] = b1e[t];
    Cw[1][t] = w1c[t * 3];
    Cw[2][t] = w1c[t * 3 + 1];
    Cw[3][t] = w1c[t * 3 + 2];
  }
  __syncthreads();

  // ---- H-ify in MFMA-fragment access pattern (each uint4 cell RMW'd by exactly one thread) ----
#pragma unroll
  for (int cc2 = 0; cc2 < 2; cc2++) {
    int ch = (wave * 2 + cc2) * 4 + kg;     // logical chunk 0..31
    int o0 = ch * 8;
    float b0[8], wx[8], wy[8], wz[8];
#pragma unroll
    for (int j = 0; j < 8; j++) {           // broadcast reads
      b0[j] = Cw[0][o0 + j];
      wx[j] = Cw[1][o0 + j];
      wy[j] = Cw[2][o0 + j];
      wz[j] = Cw[3][o0 + j];
    }
#pragma unroll
    for (int mi = 0; mi < 4; mi++) {
      int r = mi * 16 + lr;
      float cx = Xc[0][r], cy = Xc[1][r], cz = Xc[2][r];
      unsigned short* p = &Xf[r * 256 + (ch ^ (r & 7)) * 8];
      uint4 v = *(uint4*)p;
      unsigned short* e = (unsigned short*)&v;
#pragma unroll
      for (int j = 0; j < 8; j++) {
        float h = bf2f(e[j]) + b0[j] + cx * wx[j] + cy * wy[j] + cz * wz[j];
        e[j] = f2bf_cvt(fmaxf(h, 0.f));
      }
      *(uint4*)p = v;
    }
  }
  __syncthreads();

  // ---- layer 2: [64x256]x[256x256] from H (same swizzle) ----
  f32x4 acc[4][4];
#pragma unroll
  for (int mi = 0; mi < 4; mi++)
#pragma unroll
    for (int ni = 0; ni < 4; ni++) acc[mi][ni] = (f32x4){0.f, 0.f, 0.f, 0.f};
#pragma unroll
  for (int kk = 0; kk < 8; kk++) {
    bf16x8 w[4];
#pragma unroll
    for (int ni = 0; ni < 4; ni++)
      w[ni] = *(const bf16x8*)&W2b[(size_t)(wcol + ni * 16 + lr) * 256 + kk * 32 + kg * 8];
    bf16x8 a[4];
#pragma unroll
    for (int mi = 0; mi < 4; mi++) {
      int r = mi * 16 + lr;
      int cs = ((kk * 4 + kg) ^ (r & 7)) * 8;
      a[mi] = *(const bf16x8*)&Xf[r * 256 + cs];
    }
#pragma unroll
    for (int mi = 0; mi < 4; mi++)
#pragma unroll
      for (int ni = 0; ni < 4; ni++)
        acc[mi][ni] = __builtin_amdgcn_mfma_f32_16x16x32_bf16(a[mi], w[ni], acc[mi][ni], 0, 0, 0);
  }
  // ---- epilogue 2: bias + relu + max over 64 samples -> out[b][o][m] ----
  {
    int m = bm & (Mm - 1);
#pragma unroll
    for (int ni = 0; ni < 4; ni++) {
      float bv = b2e[wcol + ni * 16 + lr];
      float v = 0.f;  // relu(max) == max(relu)
#pragma unroll
      for (int mi = 0; mi < 4; mi++)
#pragma unroll
        for (int j = 0; j < 4; j++) v = fmaxf(v, acc[mi][ni][j] + bv);
      v = fmaxf(v, __shfl_xor(v, 16));
      v = fmaxf(v, __shfl_xor(v, 32));
      if (kg == 0)
        out[((size_t)b * 256 + wcol + ni * 16 + lr) * Mm + m] = v;
    }
  }
}

extern "C" void kernel_launch(void* const* d_in, const int* in_sizes, int n_in,
                              void* d_out, int out_size, void* d_ws, size_t ws_size,
                              hipStream_t stream) {
  (void)in_sizes; (void)n_in; (void)out_size; (void)ws_size;
  const float* xyz     = (const float*)d_in[0];
  const float* new_xyz = (const float*)d_in[1];
  const float* feats   = (const float*)d_in[2];
  const float* W1 = (const float*)d_in[3];
  const float* b1 = (const float*)d_in[4];
  const float* g1 = (const float*)d_in[5];
  const float* be1 = (const float*)d_in[6];
  const float* m1 = (const float*)d_in[7];
  const float* v1 = (const float*)d_in[8];
  const float* W2 = (const float*)d_in[9];
  const float* b2 = (const float*)d_in[10];
  const float* g2 = (const float*)d_in[11];
  const float* be2 = (const float*)d_in[12];
  const float* m2 = (const float*)d_in[13];
  const float* v2 = (const float*)d_in[14];
  float* out = (float*)d_out;

  char* ws = (char*)d_ws;
  unsigned short* W1b   = (unsigned short*)(ws + 0);         // 131072 B
  unsigned short* W2b   = (unsigned short*)(ws + 131072);    // 131072 B
  float*          w1c   = (float*)(ws + 262144);             // 3072 B
  float*          b1e   = (float*)(ws + 265216);             // 1024 B
  float*          b2e   = (float*)(ws + 266240);             // 1024 B
  unsigned short* X1all = (unsigned short*)(ws + 267264);    // 33554432 B
  int*            idx   = (int*)(ws + 33821696);             // 1048576 B (end ~34.9 MB)

  prep_kernel<<<256, 256, 0, stream>>>(
      W1, b1, g1, be1, m1, v1, W2, b2, g2, be2, m2, v2, W1b, w1c, b1e, W2b, b2e);
  k2_kernel<<<1024 + 1024, 256, 0, stream>>>(xyz, new_xyz, feats, W1b, X1all, idx);
  fused_kernel<<<Bb * Mm, 256, 0, stream>>>(X1all, xyz, new_xyz, idx,
                                            w1c, b1e, W2b, b2e, out);
}

// Round 29
// 145.860 us; speedup vs baseline: 1.0080x; 1.0080x over previous
//
#include <hip/hip_runtime.h>
#include <stdint.h>

typedef __bf16 bf16x8 __attribute__((ext_vector_type(8)));
typedef float f32x4 __attribute__((ext_vector_type(4)));

#define NSAMPLE 64
static constexpr int Bb = 4, Nn = 16384, Mm = 1024, Cc = 256;

__device__ __forceinline__ unsigned short f2bf(float f) {   // exact RTNE via bit ops (cold paths)
  unsigned int u = __builtin_bit_cast(unsigned int, f);
  u = u + 0x7fffu + ((u >> 16) & 1u);
  return (unsigned short)(u >> 16);
}
__device__ __forceinline__ unsigned short f2bf_cvt(float f) {  // hardware cvt (hot paths)
  return __builtin_bit_cast(unsigned short, (__bf16)f);
}
__device__ __forceinline__ float bf2f(unsigned short u) {
  return __builtin_bit_cast(float, (unsigned int)u << 16);
}

// async global->LDS, 16B per lane; LDS dest = wave-uniform base + lane*16
__device__ __forceinline__ void gload_lds16(const void* g, void* lds) {
  __builtin_amdgcn_global_load_lds(
      (const __attribute__((address_space(1))) uint32_t*)g,
      (__attribute__((address_space(3))) uint32_t*)lds, 16, 0, 0);
}

// ---- prep: SEPARATE LAUNCH (k2's X1all consumes W1b; launch boundary = the only ordering) ----
__global__ void prep_kernel(const float* __restrict__ W1, const float* __restrict__ b1,
                            const float* __restrict__ g1, const float* __restrict__ be1,
                            const float* __restrict__ m1, const float* __restrict__ v1,
                            const float* __restrict__ W2, const float* __restrict__ b2,
                            const float* __restrict__ g2, const float* __restrict__ be2,
                            const float* __restrict__ m2, const float* __restrict__ v2,
                            unsigned short* __restrict__ W1b, float* __restrict__ w1c,
                            float* __restrict__ b1e,
                            unsigned short* __restrict__ W2b, float* __restrict__ b2e) {
  int t = blockIdx.x * 256 + threadIdx.x;   // 65536 threads
  {
    int o = t >> 8, k = t & 255;
    float s1 = g1[o] / sqrtf(v1[o] + 1e-5f);
    W1b[t] = f2bf(W1[o * 259 + 3 + k] * s1);
    float s2 = g2[o] / sqrtf(v2[o] + 1e-5f);
    W2b[t] = f2bf(W2[t] * s2);
  }
  if (t < 256 * 3) {
    int o = t / 3, c = t - o * 3;
    float s = g1[o] / sqrtf(v1[o] + 1e-5f);
    w1c[t] = W1[o * 259 + c] * s;
  }
  if (t < 256) {
    float s1 = g1[t] / sqrtf(v1[t] + 1e-5f);
    b1e[t] = s1 * (b1[t] - m1[t]) + be1[t];
    float s2 = g2[t] / sqrtf(v2[t] + 1e-5f);
    b2e[t] = s2 * (b2[t] - m2[t]) + be2[t];
  }
}

// ---- K2: blocks 0..1023 ballq; 1024..2047 X1all GEMM (R28 verbatim) -------------------------
__global__ __launch_bounds__(256, 4) void k2_kernel(
    const float* __restrict__ xyz, const float* __restrict__ new_xyz,
    const float* __restrict__ feats, const unsigned short* __restrict__ W1b,
    unsigned short* __restrict__ X1all, int* __restrict__ idx) {
  __shared__ __align__(16) char smem[32768 + 64];
  int bx = blockIdx.x;
  int t = threadIdx.x;
  if (bx < 1024) {
    int* wl = (int*)smem;               // [(qi*4+w)*64+slot]
    int* wcnt = (int*)(smem + 32768);   // [qi*4+w]
    const float r2 = (float)(0.08 * 0.08);
    int bm0 = bx * 4;
    int lane = t & 63, w = t >> 6;
    int b = bm0 >> 10;
    float qx[4], qy[4], qz[4], qq[4];
    int cnt[4];
#pragma unroll
    for (int qi = 0; qi < 4; qi++) {
      qx[qi] = new_xyz[(bm0 + qi) * 3];
      qy[qi] = new_xyz[(bm0 + qi) * 3 + 1];
      qz[qi] = new_xyz[(bm0 + qi) * 3 + 2];
      qq[qi] = __fadd_rn(__fadd_rn(__fmul_rn(qx[qi], qx[qi]), __fmul_rn(qy[qi], qy[qi])),
                         __fmul_rn(qz[qi], qz[qi]));
      cnt[qi] = 0;
    }
    const float* P = xyz + ((size_t)b * Nn + w * 4096) * 3;
    for (int n0 = 0; n0 < 4096; n0 += 64) {
      const float* pp = P + (n0 + lane) * 3;
      float x = pp[0], y = pp[1], z = pp[2];
      float p2 = __fadd_rn(__fadd_rn(__fmul_rn(x, x), __fmul_rn(y, y)), __fmul_rn(z, z));
#pragma unroll
      for (int qi = 0; qi < 4; qi++) {
        if (cnt[qi] >= NSAMPLE) continue;   // wave-uniform
        float dt = __fadd_rn(__fadd_rn(__fmul_rn(qx[qi], x), __fmul_rn(qy[qi], y)),
                             __fmul_rn(qz[qi], z));
        float d2 = __fsub_rn(__fadd_rn(qq[qi], p2), __fmul_rn(2.f, dt));
        bool valid = d2 < r2;
        unsigned long long mask = __ballot(valid);
        if (mask) {
          if (valid) {
            int pos = cnt[qi] + __popcll(mask & ((1ull << lane) - 1ull));
            if (pos < NSAMPLE) wl[(qi * 4 + w) * 64 + pos] = w * 4096 + n0 + lane;
          }
          cnt[qi] += (int)__popcll(mask);
        }
      }
      if (cnt[0] >= NSAMPLE && cnt[1] >= NSAMPLE && cnt[2] >= NSAMPLE && cnt[3] >= NSAMPLE)
        break;
    }
    if (lane == 0) {
#pragma unroll
      for (int qi = 0; qi < 4; qi++) wcnt[qi * 4 + w] = cnt[qi];
    }
    __syncthreads();
    {
      int qi = t >> 6, s = t & 63;
      int c0 = wcnt[qi * 4], c1 = wcnt[qi * 4 + 1], c2 = wcnt[qi * 4 + 2], c3 = wcnt[qi * 4 + 3];
      int tot = c0 + c1 + c2 + c3;
      int cc = tot < NSAMPLE ? tot : NSAMPLE;
      int v;
      if (s < cc) {
        if (s < c0) v = wl[(qi * 4 + 0) * 64 + s];
        else if (s < c0 + c1) v = wl[(qi * 4 + 1) * 64 + s - c0];
        else if (s < c0 + c1 + c2) v = wl[(qi * 4 + 2) * 64 + s - c0 - c1];
        else v = wl[(qi * 4 + 3) * 64 + s - c0 - c1 - c2];
      } else {
        v = (c0 > 0) ? wl[(qi * 4 + 0) * 64] : (c1 > 0) ? wl[(qi * 4 + 1) * 64]
          : (c2 > 0) ? wl[(qi * 4 + 2) * 64] : (c3 > 0) ? wl[(qi * 4 + 3) * 64] : 0;
      }
      idx[(size_t)(bm0 + qi) * NSAMPLE + s] = v;
    }
    return;
  }
  // ---------------- X1all GEMM, 64-row tile; full-wave-coalesced, hardware cvt ----------------
  unsigned short* Xf = (unsigned short*)smem;   // [64][256] swizzled bf16 (32 KB)
  int xb = bx - 1024;                            // 0..1023
  int b = xb >> 8, nt = xb & 255, n0 = nt * 64;
  {
    int nloc = t & 63, cgrp = t >> 6;            // one channel-group per WAVE -> 256B coalesced
    const float* src = feats + ((size_t)(b * Cc + cgrp * 64)) * Nn + n0 + nloc;
#pragma unroll
    for (int q = 0; q < 8; q++) {
      unsigned short e[8];
#pragma unroll
      for (int j = 0; j < 8; j++)
        e[j] = f2bf_cvt(src[(size_t)(q * 8 + j) * Nn]);
      int cg = cgrp * 8 + q;                     // logical chunk 0..31
      int sc = cg ^ (nloc & 7);                  // physical chunk (rule #21)
      *(uint4*)&Xf[nloc * 256 + sc * 8] = *(uint4*)e;
    }
  }
  __syncthreads();
  // [64x256]x[256x256] MFMA
  int wave = t >> 6, lane = t & 63;
  int lr = lane & 15, kg = lane >> 4;
  int wcol = wave * 64;
  f32x4 acc[4][4];
#pragma unroll
  for (int mi = 0; mi < 4; mi++)
#pragma unroll
    for (int ni = 0; ni < 4; ni++) acc[mi][ni] = (f32x4){0.f, 0.f, 0.f, 0.f};
#pragma unroll
  for (int kk = 0; kk < 8; kk++) {
    bf16x8 w[4];
#pragma unroll
    for (int ni = 0; ni < 4; ni++)
      w[ni] = *(const bf16x8*)&W1b[(size_t)(wcol + ni * 16 + lr) * 256 + kk * 32 + kg * 8];
    bf16x8 a[4];
#pragma unroll
    for (int mi = 0; mi < 4; mi++) {
      int r = mi * 16 + lr;
      int cs = ((kk * 4 + kg) ^ (r & 7)) * 8;
      a[mi] = *(const bf16x8*)&Xf[r * 256 + cs];
    }
#pragma unroll
    for (int mi = 0; mi < 4; mi++)
#pragma unroll
      for (int ni = 0; ni < 4; ni++)
        acc[mi][ni] = __builtin_amdgcn_mfma_f32_16x16x32_bf16(a[mi], w[ni], acc[mi][ni], 0, 0, 0);
  }
  __syncthreads();
  // bounce acc -> Xf LINEAR
#pragma unroll
  for (int ni = 0; ni < 4; ni++) {
    int o = wcol + ni * 16 + lr;
#pragma unroll
    for (int mi = 0; mi < 4; mi++)
#pragma unroll
      for (int j = 0; j < 4; j++) {
        int r = mi * 16 + kg * 4 + j;
        Xf[r * 256 + o] = f2bf_cvt(acc[mi][ni][j]);
      }
  }
  __syncthreads();
  // coalesced store: thread t -> row t>>2, cols (t&3)*64..+63 (8 x uint4)
  {
    int row = t >> 2, off = (t & 3) * 64;
    unsigned short* dst = X1all + ((size_t)(b * Nn + n0 + row)) * 256 + off;
#pragma unroll
    for (int i = 0; i < 8; i++)
      *(uint4*)(dst + i * 8) = *(const uint4*)&Xf[row * 256 + off + i * 8];
  }
}

// ---- fused: per-wave gather -> H-ify coupling (T14: own-rows wait via per-wave vmcnt) --------
// Wave wv gathers rows 16wv..16wv+15 (1 gload covers a 512B row pair) AND H-ifies exactly those
// rows, so only s_waitcnt vmcnt(0) on its OWN loads is needed before H-ify; the block barrier
// before H-ify is raw lgkmcnt+s_barrier (orders Xc/Cw ds_writes WITHOUT draining gather vmcnt —
// R8-proven). Coord/Cw global loads are issued BEFORE the gathers so their ds_writes' implicit
// vmcnt waits leave the gathers in flight. Full __syncthreads only before the cross-wave L2 MFMA.
__global__ __launch_bounds__(256, 4) void fused_kernel(
    const unsigned short* __restrict__ X1all, const float* __restrict__ xyz,
    const float* __restrict__ new_xyz, const int* __restrict__ idx,
    const float* __restrict__ w1c, const float* __restrict__ b1e,
    const unsigned short* __restrict__ W2b, const float* __restrict__ b2e,
    float* __restrict__ out) {
  __shared__ unsigned short Xf[64 * 256];  // 32768 B swizzled; X1 gathered -> H in place
  __shared__ float Xc[3][64];
  __shared__ float Cw[4][256];             // b1e, wx, wy, wz staged
  int t = threadIdx.x;
  int wave = t >> 6, lane = t & 63;
  int lr = lane & 15, kg = lane >> 4;
  int wcol = wave * 64;
  int bm = blockIdx.x;
  int b = bm >> 10;

  // (1) coord loads + Xc writes for OWN rows (lanes 0..15 of each wave -> rows 16wv+lane)
  if (lr < 16 && kg == 0) {  // lane < 16
    int r = wave * 16 + lane;
    int ci = idx[(size_t)bm * NSAMPLE + r];
    const float* pp = xyz + ((size_t)b * Nn + ci) * 3;
    Xc[0][r] = pp[0] - new_xyz[bm * 3];
    Xc[1][r] = pp[1] - new_xyz[bm * 3 + 1];
    Xc[2][r] = pp[2] - new_xyz[bm * 3 + 2];
  }
  // (2) Cw loads + writes (all threads; issued before gathers)
  {
    Cw[0][t] = b1e[t];
    Cw[1][t] = w1c[t * 3];
    Cw[2][t] = w1c[t * 3 + 1];
    Cw[3][t] = w1c[t * 3 + 2];
  }
  // (3) async gather: wave wv -> rows 16wv..16wv+15
  {
    int idxr = idx[(size_t)bm * NSAMPLE + wave * 16 + (lane & 15)];
#pragma unroll
    for (int i = 0; i < 8; i++) {
      int j = wave * 8 + i;                       // row pair 2j, 2j+1
      int iv = __shfl(idxr, 2 * i + (lane >> 5));
      int r7 = (2 * j + (lane >> 5)) & 7;
      int cg = (lane & 31) ^ r7;                  // swizzled global chunk (rule #21)
      gload_lds16(X1all + ((size_t)b * Nn + iv) * Cc + cg * 8, &Xf[j * 512]);
    }
  }
  // (4) raw barrier: Xc/Cw visible across waves; gather vmcnt stays in flight
  asm volatile("s_waitcnt lgkmcnt(0)\n\ts_barrier" ::: "memory");
  // (5) wait OWN gathers only (vmcnt is per-wave); fence scheduler (rule #18)
  asm volatile("s_waitcnt vmcnt(0)" ::: "memory");
  __builtin_amdgcn_sched_barrier(0);

  // (6) H-ify OWN rows, fragment-pattern: rows r = 16wv + (lr&3) + 4mi, chunks
  // ch = 16cc2 + (lr>>2)*4 + kg. Coverage: 16 rows x 32 chunks per wave, each cell once.
  // Banks: quad index = (ch ^ (r&7)) & 7 -> per quarter-wave 8 values x 2-way (free).
#pragma unroll
  for (int cc2 = 0; cc2 < 2; cc2++) {
    int ch = cc2 * 16 + (lr >> 2) * 4 + kg;  // logical chunk 0..31
    int o0 = ch * 8;
    float b0[8], wx[8], wy[8], wz[8];
#pragma unroll
    for (int j = 0; j < 8; j++) {            // broadcast reads
      b0[j] = Cw[0][o0 + j];
      wx[j] = Cw[1][o0 + j];
      wy[j] = Cw[2][o0 + j];
      wz[j] = Cw[3][o0 + j];
    }
#pragma unroll
    for (int mi = 0; mi < 4; mi++) {
      int r = wave * 16 + (lr & 3) + 4 * mi;
      float cx = Xc[0][r], cy = Xc[1][r], cz = Xc[2][r];
      unsigned short* p = &Xf[r * 256 + (ch ^ (r & 7)) * 8];
      uint4 v = *(uint4*)p;
      unsigned short* e = (unsigned short*)&v;
#pragma unroll
      for (int j = 0; j < 8; j++) {
        float h = bf2f(e[j]) + b0[j] + cx * wx[j] + cy * wy[j] + cz * wz[j];
        e[j] = f2bf_cvt(fmaxf(h, 0.f));
      }
      *(uint4*)p = v;
    }
  }
  __syncthreads();  // (7) all H visible for the cross-wave L2 MFMA

  // ---- layer 2: [64x256]x[256x256] from H (same swizzle) ----
  f32x4 acc[4][4];
#pragma unroll
  for (int mi = 0; mi < 4; mi++)
#pragma unroll
    for (int ni = 0; ni < 4; ni++) acc[mi][ni] = (f32x4){0.f, 0.f, 0.f, 0.f};
#pragma unroll
  for (int kk = 0; kk < 8; kk++) {
    bf16x8 w[4];
#pragma unroll
    for (int ni = 0; ni < 4; ni++)
      w[ni] = *(const bf16x8*)&W2b[(size_t)(wcol + ni * 16 + lr) * 256 + kk * 32 + kg * 8];
    bf16x8 a[4];
#pragma unroll
    for (int mi = 0; mi < 4; mi++) {
      int r = mi * 16 + lr;
      int cs = ((kk * 4 + kg) ^ (r & 7)) * 8;
      a[mi] = *(const bf16x8*)&Xf[r * 256 + cs];
    }
#pragma unroll
    for (int mi = 0; mi < 4; mi++)
#pragma unroll
      for (int ni = 0; ni < 4; ni++)
        acc[mi][ni] = __builtin_amdgcn_mfma_f32_16x16x32_bf16(a[mi], w[ni], acc[mi][ni], 0, 0, 0);
  }
  // ---- epilogue 2: bias + relu + max over 64 samples -> out[b][o][m] ----
  {
    int m = bm & (Mm - 1);
#pragma unroll
    for (int ni = 0; ni < 4; ni++) {
      float bv = b2e[wcol + ni * 16 + lr];
      float v = 0.f;  // relu(max) == max(relu)
#pragma unroll
      for (int mi = 0; mi < 4; mi++)
#pragma unroll
        for (int j = 0; j < 4; j++) v = fmaxf(v, acc[mi][ni][j] + bv);
      v = fmaxf(v, __shfl_xor(v, 16));
      v = fmaxf(v, __shfl_xor(v, 32));
      if (kg == 0)
        out[((size_t)b * 256 + wcol + ni * 16 + lr) * Mm + m] = v;
    }
  }
}

extern "C" void kernel_launch(void* const* d_in, const int* in_sizes, int n_in,
                              void* d_out, int out_size, void* d_ws, size_t ws_size,
                              hipStream_t stream) {
  (void)in_sizes; (void)n_in; (void)out_size; (void)ws_size;
  const float* xyz     = (const float*)d_in[0];
  const float* new_xyz = (const float*)d_in[1];
  const float* feats   = (const float*)d_in[2];
  const float* W1 = (const float*)d_in[3];
  const float* b1 = (const float*)d_in[4];
  const float* g1 = (const float*)d_in[5];
  const float* be1 = (const float*)d_in[6];
  const float* m1 = (const float*)d_in[7];
  const float* v1 = (const float*)d_in[8];
  const float* W2 = (const float*)d_in[9];
  const float* b2 = (const float*)d_in[10];
  const float* g2 = (const float*)d_in[11];
  const float* be2 = (const float*)d_in[12];
  const float* m2 = (const float*)d_in[13];
  const float* v2 = (const float*)d_in[14];
  float* out = (float*)d_out;

  char* ws = (char*)d_ws;
  unsigned short* W1b   = (unsigned short*)(ws + 0);         // 131072 B
  unsigned short* W2b   = (unsigned short*)(ws + 131072);    // 131072 B
  float*          w1c   = (float*)(ws + 262144);             // 3072 B
  float*          b1e   = (float*)(ws + 265216);             // 1024 B
  float*          b2e   = (float*)(ws + 266240);             // 1024 B
  unsigned short* X1all = (unsigned short*)(ws + 267264);    // 33554432 B
  int*            idx   = (int*)(ws + 33821696);             // 1048576 B (end ~34.9 MB)

  prep_kernel<<<256, 256, 0, stream>>>(
      W1, b1, g1, be1, m1, v1, W2, b2, g2, be2, m2, v2, W1b, w1c, b1e, W2b, b2e);
  k2_kernel<<<1024 + 1024, 256, 0, stream>>>(xyz, new_xyz, feats, W1b, X1all, idx);
  fused_kernel<<<Bb * Mm, 256, 0, stream>>>(X1all, xyz, new_xyz, idx,
                                            w1c, b1e, W2b, b2e, out);
}